// Round 4
// baseline (3392.273 us; speedup 1.0000x reference)
//
#include <hip/hip_runtime.h>
#include <cstdint>
#include <cstddef>

// ---------------------------------------------------------------------------
// AdaAttN fused kernel set, fp16 MFMA path.
//   B=4, C=KP=512, N=M=4096.
//   ws layout (fp16): Fb[4][4096][512] | Gb[4][4096][512] | VT[4][1536][4096]
//     VT rows per batch: [0..511]   = Hs (v-hat, fp16)
//                        [512..1023]= fp16(v-hat^2)   (hi)
//                        [1024..1535]= v-hat^2 - hi    (lo)  -- protects e2-mean^2
//
// R4: occupancy + locality restructure of the flash kernel.
//   - g_lds removed: each wave only read its OWN 16 G rows -> direct global
//     loads (same bytes, no vmcnt(0) drain, one less barrier per iter).
//   - F staged ONCE into LDS in fragment order (conflict-free ds_read_b128).
//   - epilogue chunked into 2x256-channel passes: LDS 73.7 KB -> 36.9 KB
//     -> 4 blocks/CU (was 2), launch_bounds(256,4) (128 VGPR; acc=96 fits).
//   - XCD swizzle: batch b -> XCDs {2b,2b+1} so per-XCD L2 serves one batch.
//   NOTE: every loop touching acc[] MUST be fully unrolled — a partial
//   unroll leaves a runtime index and demotes acc to scratch (R1/R2 bug).
// ---------------------------------------------------------------------------

typedef _Float16 f16;
typedef _Float16 f16x8 __attribute__((ext_vector_type(8)));
typedef float f32x4 __attribute__((ext_vector_type(4)));

#define LOG2E 1.44269504088896340736f

// ---------------------------------------------------------------------------
// conv_ik: out[b][i][k] = bias[k] + sum_c wm[k][c] * in[b][c][i]   (fp16 out)
// ---------------------------------------------------------------------------
__global__ __launch_bounds__(256, 2) void conv_ik(
    const float* __restrict__ in, const float* __restrict__ wm,
    const float* __restrict__ bias, f16* __restrict__ out) {
  const int i0 = blockIdx.x * 64;
  const int k0 = blockIdx.y * 64;
  const int b = blockIdx.z;
  const int tid = threadIdx.x;
  const int lane = tid & 63;
  const int wv = tid >> 6;
  const int l15 = lane & 15;
  const int quad = lane >> 4;

  __shared__ __align__(16) f16 a_lds[64 * 40];  // [i][c] stride 40 (pad)

  const float* inb = in + (size_t)b * (512 * 4096);

  f32x4 acc[4];
#pragma unroll
  for (int t = 0; t < 4; ++t) acc[t] = f32x4{0.f, 0.f, 0.f, 0.f};

  for (int cs = 0; cs < 512; cs += 32) {
    __syncthreads();
#pragma unroll
    for (int rep = 0; rep < 2; ++rep) {
      int chunk = tid + rep * 256;  // 0..511
      int cc = chunk >> 4;          // 0..31
      int f4 = chunk & 15;          // 0..15
      float4 v = *(const float4*)(inb + (size_t)(cs + cc) * 4096 + i0 + f4 * 4);
      int ib = f4 * 4;
      a_lds[(ib + 0) * 40 + cc] = (f16)v.x;
      a_lds[(ib + 1) * 40 + cc] = (f16)v.y;
      a_lds[(ib + 2) * 40 + cc] = (f16)v.z;
      a_lds[(ib + 3) * 40 + cc] = (f16)v.w;
    }
    __syncthreads();
    f16x8 af = *(const f16x8*)&a_lds[(wv * 16 + l15) * 40 + quad * 8];
#pragma unroll
    for (int ct = 0; ct < 4; ++ct) {
      const float* wp = wm + (size_t)(k0 + ct * 16 + l15) * 512 + cs + quad * 8;
      float4 w0 = *(const float4*)wp;
      float4 w1 = *(const float4*)(wp + 4);
      f16x8 bf;
      bf[0] = (f16)w0.x; bf[1] = (f16)w0.y; bf[2] = (f16)w0.z; bf[3] = (f16)w0.w;
      bf[4] = (f16)w1.x; bf[5] = (f16)w1.y; bf[6] = (f16)w1.z; bf[7] = (f16)w1.w;
      acc[ct] = __builtin_amdgcn_mfma_f32_16x16x32_f16(af, bf, acc[ct], 0, 0, 0);
    }
  }
#pragma unroll
  for (int ct = 0; ct < 4; ++ct) {
    int k = k0 + ct * 16 + l15;
    float bv = bias[k];
#pragma unroll
    for (int r = 0; r < 4; ++r) {
      int i = i0 + wv * 16 + quad * 4 + r;
      out[((size_t)b * 4096 + i) * 512 + k] = (f16)(acc[ct][r] + bv);
    }
  }
}

// ---------------------------------------------------------------------------
// conv_vt: val = bias[k] + sum_c wm[k][c] * in[b][c][i]
//   VT[b][k][i]=fp16(val); VT[b][512+k][i]=hi(val^2); VT[b][1024+k][i]=lo
// ---------------------------------------------------------------------------
__global__ __launch_bounds__(256, 2) void conv_vt(
    const float* __restrict__ in, const float* __restrict__ wm,
    const float* __restrict__ bias, f16* __restrict__ vt) {
  const int i0 = blockIdx.x * 64;
  const int k0 = blockIdx.y * 64;
  const int b = blockIdx.z;
  const int tid = threadIdx.x;
  const int lane = tid & 63;
  const int wv = tid >> 6;
  const int l15 = lane & 15;
  const int quad = lane >> 4;

  __shared__ __align__(16) f16 b_lds[64 * 40];  // [i][c] stride 40

  const float* inb = in + (size_t)b * (512 * 4096);

  f32x4 acc[4];
#pragma unroll
  for (int t = 0; t < 4; ++t) acc[t] = f32x4{0.f, 0.f, 0.f, 0.f};

  for (int cs = 0; cs < 512; cs += 32) {
    __syncthreads();
#pragma unroll
    for (int rep = 0; rep < 2; ++rep) {
      int chunk = tid + rep * 256;
      int cc = chunk >> 4;
      int f4 = chunk & 15;
      float4 v = *(const float4*)(inb + (size_t)(cs + cc) * 4096 + i0 + f4 * 4);
      int ib = f4 * 4;
      b_lds[(ib + 0) * 40 + cc] = (f16)v.x;
      b_lds[(ib + 1) * 40 + cc] = (f16)v.y;
      b_lds[(ib + 2) * 40 + cc] = (f16)v.z;
      b_lds[(ib + 3) * 40 + cc] = (f16)v.w;
    }
    __syncthreads();
    const float* wp = wm + (size_t)(k0 + wv * 16 + l15) * 512 + cs + quad * 8;
    float4 w0 = *(const float4*)wp;
    float4 w1 = *(const float4*)(wp + 4);
    f16x8 af;
    af[0] = (f16)w0.x; af[1] = (f16)w0.y; af[2] = (f16)w0.z; af[3] = (f16)w0.w;
    af[4] = (f16)w1.x; af[5] = (f16)w1.y; af[6] = (f16)w1.z; af[7] = (f16)w1.w;
#pragma unroll
    for (int ct = 0; ct < 4; ++ct) {
      f16x8 bfr = *(const f16x8*)&b_lds[(ct * 16 + l15) * 40 + quad * 8];
      acc[ct] = __builtin_amdgcn_mfma_f32_16x16x32_f16(af, bfr, acc[ct], 0, 0, 0);
    }
  }
  f16* vtb = vt + (size_t)b * 1536 * 4096;
#pragma unroll
  for (int ct = 0; ct < 4; ++ct) {
    int i = i0 + ct * 16 + l15;
#pragma unroll
    for (int r = 0; r < 4; ++r) {
      int k = k0 + wv * 16 + quad * 4 + r;
      float val = acc[ct][r] + bias[k];
      f16 vh = (f16)val;
      float vf = (float)vh;
      float sq = vf * vf;
      f16 sqh = (f16)sq;
      f16 sql = (f16)(sq - (float)sqh);
      vtb[(size_t)k * 4096 + i] = vh;
      vtb[(size_t)(512 + k) * 4096 + i] = sqh;
      vtb[(size_t)(1024 + k) * 4096 + i] = sql;
    }
  }
}

// ---------------------------------------------------------------------------
// adaattn_flash: per block = 16 Q-rows of one batch; 4 waves; M-tiles of 64.
//   wave w owns V cols [w*384, w*384+384) (24 16x16 acc tiles, 96 regs).
//   F staged once in LDS (fragment order). G + V direct per-lane global loads.
//   LDS 36.9 KB -> 4 blocks/CU; 2 barriers per m-iter.
// ---------------------------------------------------------------------------
__global__ __launch_bounds__(256, 4) void adaattn_flash(
    const f16* __restrict__ Fb, const f16* __restrict__ Gb,
    const f16* __restrict__ VT, const float* __restrict__ cx,
    float* __restrict__ out) {
  // XCD swizzle: assuming round-robin blockIdx->XCD, batch b lands on
  // XCDs {2b, 2b+1} (perf heuristic only; correctness independent).
  const int id = blockIdx.x;
  const int b = (id >> 1) & 3;
  const int n0 = (((id >> 3) << 1) | (id & 1)) * 16;
  const int tid = threadIdx.x;
  const int lane = tid & 63;
  const int wv = tid >> 6;
  const int l15 = lane & 15;
  const int quad = lane >> 4;

  // main: f_lds[16][64][8] (16384) | p_lds[16][72] (2304) | smax | ssum
  // epilogue (aliased): meanL[256][18] (18432) | e2L[256][18] (18432)
  __shared__ __align__(16) char smem[36864];
  f16* f_lds = (f16*)smem;                 // fragment-ordered F tile
  f16* p_lds = (f16*)(smem + 16384);       // [16 rows][72]
  float* smax = (float*)(smem + 18688);    // [4][16]
  float* ssum = (float*)(smem + 18944);    // [4][16]

  // stage F once: f_lds[ks*512 + lane*8 .. +8] = A-frag(lane) at K-step ks
  {
    const f16* fbase = Fb + ((size_t)b * 4096 + n0) * 512;
#pragma unroll
    for (int rep = 0; rep < 4; ++rep) {
      int fid = tid + rep * 256;  // 0..1023 = (ks, lane)
      int ks = fid >> 6;
      int ln = fid & 63;
      f16x8 v = *(const f16x8*)(fbase + (size_t)(ln & 15) * 512 + ks * 32 +
                                (ln >> 4) * 8);
      *(f16x8*)&f_lds[fid * 8] = v;
    }
  }

  f32x4 acc[24];
#pragma unroll
  for (int t = 0; t < 24; ++t) acc[t] = f32x4{0.f, 0.f, 0.f, 0.f};
  float m_run[4] = {-1e30f, -1e30f, -1e30f, -1e30f};
  float l_run[4] = {0.f, 0.f, 0.f, 0.f};

  // G fragment base: wave w reads its own 16 rows [m0+wv*16 .. +16)
  const f16* gbase = Gb + ((size_t)b * 4096 + wv * 16 + l15) * 512 + quad * 8;
  const f16* vb = VT + ((size_t)b * 1536 + (size_t)wv * 384 + l15) * 4096;

  __syncthreads();  // f_lds ready

  for (int m0 = 0; m0 < 4096; m0 += 64) {
    // QK: wave w -> logit cols [w*16, w*16+16), K=512
    f32x4 lg = f32x4{0.f, 0.f, 0.f, 0.f};
    {
      const f16* gp = gbase + (size_t)m0 * 512;
#pragma unroll
      for (int ks = 0; ks < 16; ++ks) {
        f16x8 ff = *(const f16x8*)&f_lds[ks * 512 + lane * 8];
        f16x8 gf = *(const f16x8*)(gp + ks * 32);
        lg = __builtin_amdgcn_mfma_f32_16x16x32_f16(ff, gf, lg, 0, 0, 0);
      }
    }

    // wave-local row max over 16 cols (butterfly within 16-lane groups)
    float tm[4];
#pragma unroll
    for (int r = 0; r < 4; ++r) {
      float v = lg[r];
      v = fmaxf(v, __shfl_xor(v, 1));
      v = fmaxf(v, __shfl_xor(v, 2));
      v = fmaxf(v, __shfl_xor(v, 4));
      v = fmaxf(v, __shfl_xor(v, 8));
      tm[r] = v;
    }
    if (l15 == 0) {
#pragma unroll
      for (int r = 0; r < 4; ++r) smax[wv * 16 + quad * 4 + r] = tm[r];
    }
    __syncthreads();  // smax ready; also guards p_lds reuse from prev iter

    float alpha[4], ts[4];
#pragma unroll
    for (int r = 0; r < 4; ++r) {
      int row = quad * 4 + r;
      float mt = fmaxf(fmaxf(smax[row], smax[16 + row]),
                       fmaxf(smax[32 + row], smax[48 + row]));
      float mn = fmaxf(m_run[r], mt);
      alpha[r] = exp2f((m_run[r] - mn) * LOG2E);
      m_run[r] = mn;
      float p = exp2f((lg[r] - mn) * LOG2E);
      f16 ph = (f16)p;  // round first so weights & sums agree exactly
      p = (float)ph;
      p_lds[row * 72 + wv * 16 + l15] = ph;
      float s = p;
      s += __shfl_xor(s, 1);
      s += __shfl_xor(s, 2);
      s += __shfl_xor(s, 4);
      s += __shfl_xor(s, 8);
      ts[r] = s;
    }
    if (l15 == 0) {
#pragma unroll
      for (int r = 0; r < 4; ++r) ssum[wv * 16 + quad * 4 + r] = ts[r];
    }
    // rescale accumulators by alpha; skip when all alpha == 1 (exact identity)
    if (__any(alpha[0] != 1.f || alpha[1] != 1.f ||
              alpha[2] != 1.f || alpha[3] != 1.f)) {
#pragma unroll
      for (int t = 0; t < 24; ++t) {
#pragma unroll
        for (int r = 0; r < 4; ++r) acc[t][r] *= alpha[r];
      }
    }
    __syncthreads();  // p_lds + ssum ready

#pragma unroll
    for (int r = 0; r < 4; ++r) {
      int row = quad * 4 + r;
      l_run[r] = l_run[r] * alpha[r] +
                 (ssum[row] + ssum[16 + row] + ssum[32 + row] + ssum[48 + row]);
    }

    // PV: A = P (from LDS), B = VT rows direct from global (L2-resident)
    // FULL unroll: constant acc indices (partial unroll => scratch demotion)
    f16x8 pf0 = *(const f16x8*)&p_lds[l15 * 72 + quad * 8];
    f16x8 pf1 = *(const f16x8*)&p_lds[l15 * 72 + 32 + quad * 8];
    const f16* vp = vb + m0 + quad * 8;
#pragma unroll
    for (int ct = 0; ct < 24; ++ct) {
      f16x8 v0 = *(const f16x8*)(vp + (size_t)ct * (16 * 4096));
      f16x8 v1 = *(const f16x8*)(vp + (size_t)ct * (16 * 4096) + 32);
      acc[ct] = __builtin_amdgcn_mfma_f32_16x16x32_f16(pf0, v0, acc[ct], 0, 0, 0);
      acc[ct] = __builtin_amdgcn_mfma_f32_16x16x32_f16(pf1, v1, acc[ct], 0, 0, 0);
    }
  }

  // ---------------- epilogue (2 passes of 256 channels) ----------------
  __syncthreads();  // all p_lds/f_lds reads done before aliasing as meanL/e2L
  float inv[4];
#pragma unroll
  for (int r = 0; r < 4; ++r) inv[r] = 1.0f / l_run[r];

  float* meanL = (float*)smem;           // [256][18]
  float* e2L = (float*)(smem + 18432);   // [256][18]

#pragma unroll
  for (int half = 0; half < 2; ++half) {
    // phase 1: write mean (grp 0) and e2-hi (grp 1) for this channel half
#pragma unroll
    for (int ct = 0; ct < 24; ++ct) {
      int vcol = wv * 384 + ct * 16 + l15;
      int grp = vcol >> 9;
      int c = vcol & 511;
      if (grp < 2 && (c >> 8) == half) {
        float* dst = (grp == 0) ? meanL : e2L;
#pragma unroll
        for (int r = 0; r < 4; ++r)
          dst[(c & 255) * 18 + quad * 4 + r] = acc[ct][r] * inv[r];
      }
    }
    __syncthreads();
    // phase 2: add e2-lo (grp 2)
#pragma unroll
    for (int ct = 0; ct < 24; ++ct) {
      int vcol = wv * 384 + ct * 16 + l15;
      int grp = vcol >> 9;
      int c = vcol & 511;
      if (grp == 2 && (c >> 8) == half) {
#pragma unroll
        for (int r = 0; r < 4; ++r)
          e2L[(c & 255) * 18 + quad * 4 + r] += acc[ct][r] * inv[r];
      }
    }
    __syncthreads();

    // out[b][half*256 + c][n0+nl] = std * c_x + mean
#pragma unroll 4
    for (int rep = 0; rep < 16; ++rep) {
      int idx = tid + rep * 256;  // 0..4095
      int cl = idx >> 4;          // 0..255
      int nl = idx & 15;
      float m = meanL[cl * 18 + nl];
      float e2v = e2L[cl * 18 + nl];
      float sd = sqrtf(fmaxf(e2v - m * m, 0.f));
      size_t gi = ((size_t)b * 512 + half * 256 + cl) * 4096 + n0 + nl;
      out[gi] = sd * cx[gi] + m;
    }
    __syncthreads();  // before next half reuses meanL/e2L
  }
}

// ---------------------------------------------------------------------------
extern "C" void kernel_launch(void* const* d_in, const int* in_sizes, int n_in,
                              void* d_out, int out_size, void* d_ws, size_t ws_size,
                              hipStream_t stream) {
  (void)in_sizes; (void)n_in; (void)out_size;
  const float* c_x  = (const float*)d_in[0];
  const float* s_x  = (const float*)d_in[1];
  const float* c_1x = (const float*)d_in[2];
  const float* s_1x = (const float*)d_in[3];
  const float* f_w  = (const float*)d_in[4];
  const float* f_b  = (const float*)d_in[5];
  const float* g_w  = (const float*)d_in[6];
  const float* g_b  = (const float*)d_in[7];
  const float* h_w  = (const float*)d_in[8];
  const float* h_b  = (const float*)d_in[9];
  float* out = (float*)d_out;

  const size_t fe = (size_t)4 * 4096 * 512;  // elements per F/G buffer
  f16* Fb = (f16*)d_ws;
  f16* Gb = Fb + fe;
  f16* VT = Gb + fe;
  const size_t need = fe * 2 * sizeof(f16) * 2 + (size_t)4 * 1536 * 4096 * sizeof(f16);
  if (ws_size < need) return;  // 80 MiB required; fail loudly (output stays poisoned)

  dim3 blk(256);
  dim3 gP(64, 8, 4);
  conv_ik<<<gP, blk, 0, stream>>>(c_1x, f_w, f_b, Fb);
  conv_ik<<<gP, blk, 0, stream>>>(s_1x, g_w, g_b, Gb);
  conv_vt<<<gP, blk, 0, stream>>>(s_x, h_w, h_b, VT);
  adaattn_flash<<<dim3(1024), blk, 0, stream>>>(Fb, Gb, VT, c_x, out);
}

// Round 5
// 2503.371 us; speedup vs baseline: 1.3551x; 1.3551x over previous
//
#include <hip/hip_runtime.h>
#include <cstdint>
#include <cstddef>

// ---------------------------------------------------------------------------
// AdaAttN fused kernel set, fp16 MFMA path.
//   B=4, C=KP=512, N=M=4096.
//   ws layout (fp16): Fb[4][4096][512] | Gb[4][4096][512] | VT[4][1536][4096]
//     VT rows per batch: [0..511]   = Hs (v-hat, fp16)
//                        [512..1023]= fp16(v-hat^2)   (hi)
//                        [1024..1535]= v-hat^2 - hi    (lo)  -- protects e2-mean^2
//
// R5: Q-tile 32 via 512-thread blocks (8 waves = 2 rowgroups x 4 colgroups).
//   - halves V L2/L3 traffic (12.6 -> 6.3 GB) and block count vs R3.
//   - launch_bounds(512,2): 256-VGPR cap -> acc[24]=96 regs CANNOT spill
//     (R4 failed because (256,4)'s 128-cap forced wholesale acc demotion).
//   - twin waves (same cg, both rg) read identical G/V bytes ~in lockstep
//     -> L1 absorbs the duplicate.
//   NOTE: every loop touching acc[] MUST be fully unrolled — a partial
//   unroll leaves a runtime index and demotes acc to scratch (R1/R2 bug).
// ---------------------------------------------------------------------------

typedef _Float16 f16;
typedef _Float16 f16x8 __attribute__((ext_vector_type(8)));
typedef float f32x4 __attribute__((ext_vector_type(4)));

#define LOG2E 1.44269504088896340736f

// ---------------------------------------------------------------------------
// conv_ik: out[b][i][k] = bias[k] + sum_c wm[k][c] * in[b][c][i]   (fp16 out)
// ---------------------------------------------------------------------------
__global__ __launch_bounds__(256, 2) void conv_ik(
    const float* __restrict__ in, const float* __restrict__ wm,
    const float* __restrict__ bias, f16* __restrict__ out) {
  const int i0 = blockIdx.x * 64;
  const int k0 = blockIdx.y * 64;
  const int b = blockIdx.z;
  const int tid = threadIdx.x;
  const int lane = tid & 63;
  const int wv = tid >> 6;
  const int l15 = lane & 15;
  const int quad = lane >> 4;

  __shared__ __align__(16) f16 a_lds[64 * 40];  // [i][c] stride 40 (pad)

  const float* inb = in + (size_t)b * (512 * 4096);

  f32x4 acc[4];
#pragma unroll
  for (int t = 0; t < 4; ++t) acc[t] = f32x4{0.f, 0.f, 0.f, 0.f};

  for (int cs = 0; cs < 512; cs += 32) {
    __syncthreads();
#pragma unroll
    for (int rep = 0; rep < 2; ++rep) {
      int chunk = tid + rep * 256;  // 0..511
      int cc = chunk >> 4;          // 0..31
      int f4 = chunk & 15;          // 0..15
      float4 v = *(const float4*)(inb + (size_t)(cs + cc) * 4096 + i0 + f4 * 4);
      int ib = f4 * 4;
      a_lds[(ib + 0) * 40 + cc] = (f16)v.x;
      a_lds[(ib + 1) * 40 + cc] = (f16)v.y;
      a_lds[(ib + 2) * 40 + cc] = (f16)v.z;
      a_lds[(ib + 3) * 40 + cc] = (f16)v.w;
    }
    __syncthreads();
    f16x8 af = *(const f16x8*)&a_lds[(wv * 16 + l15) * 40 + quad * 8];
#pragma unroll
    for (int ct = 0; ct < 4; ++ct) {
      const float* wp = wm + (size_t)(k0 + ct * 16 + l15) * 512 + cs + quad * 8;
      float4 w0 = *(const float4*)wp;
      float4 w1 = *(const float4*)(wp + 4);
      f16x8 bf;
      bf[0] = (f16)w0.x; bf[1] = (f16)w0.y; bf[2] = (f16)w0.z; bf[3] = (f16)w0.w;
      bf[4] = (f16)w1.x; bf[5] = (f16)w1.y; bf[6] = (f16)w1.z; bf[7] = (f16)w1.w;
      acc[ct] = __builtin_amdgcn_mfma_f32_16x16x32_f16(af, bf, acc[ct], 0, 0, 0);
    }
  }
#pragma unroll
  for (int ct = 0; ct < 4; ++ct) {
    int k = k0 + ct * 16 + l15;
    float bv = bias[k];
#pragma unroll
    for (int r = 0; r < 4; ++r) {
      int i = i0 + wv * 16 + quad * 4 + r;
      out[((size_t)b * 4096 + i) * 512 + k] = (f16)(acc[ct][r] + bv);
    }
  }
}

// ---------------------------------------------------------------------------
// conv_vt: val = bias[k] + sum_c wm[k][c] * in[b][c][i]
//   VT[b][k][i]=fp16(val); VT[b][512+k][i]=hi(val^2); VT[b][1024+k][i]=lo
// ---------------------------------------------------------------------------
__global__ __launch_bounds__(256, 2) void conv_vt(
    const float* __restrict__ in, const float* __restrict__ wm,
    const float* __restrict__ bias, f16* __restrict__ vt) {
  const int i0 = blockIdx.x * 64;
  const int k0 = blockIdx.y * 64;
  const int b = blockIdx.z;
  const int tid = threadIdx.x;
  const int lane = tid & 63;
  const int wv = tid >> 6;
  const int l15 = lane & 15;
  const int quad = lane >> 4;

  __shared__ __align__(16) f16 b_lds[64 * 40];  // [i][c] stride 40

  const float* inb = in + (size_t)b * (512 * 4096);

  f32x4 acc[4];
#pragma unroll
  for (int t = 0; t < 4; ++t) acc[t] = f32x4{0.f, 0.f, 0.f, 0.f};

  for (int cs = 0; cs < 512; cs += 32) {
    __syncthreads();
#pragma unroll
    for (int rep = 0; rep < 2; ++rep) {
      int chunk = tid + rep * 256;
      int cc = chunk >> 4;
      int f4 = chunk & 15;
      float4 v = *(const float4*)(inb + (size_t)(cs + cc) * 4096 + i0 + f4 * 4);
      int ib = f4 * 4;
      b_lds[(ib + 0) * 40 + cc] = (f16)v.x;
      b_lds[(ib + 1) * 40 + cc] = (f16)v.y;
      b_lds[(ib + 2) * 40 + cc] = (f16)v.z;
      b_lds[(ib + 3) * 40 + cc] = (f16)v.w;
    }
    __syncthreads();
    const float* wp = wm + (size_t)(k0 + wv * 16 + l15) * 512 + cs + quad * 8;
    float4 w0 = *(const float4*)wp;
    float4 w1 = *(const float4*)(wp + 4);
    f16x8 af;
    af[0] = (f16)w0.x; af[1] = (f16)w0.y; af[2] = (f16)w0.z; af[3] = (f16)w0.w;
    af[4] = (f16)w1.x; af[5] = (f16)w1.y; af[6] = (f16)w1.z; af[7] = (f16)w1.w;
#pragma unroll
    for (int ct = 0; ct < 4; ++ct) {
      f16x8 bfr = *(const f16x8*)&b_lds[(ct * 16 + l15) * 40 + quad * 8];
      acc[ct] = __builtin_amdgcn_mfma_f32_16x16x32_f16(af, bfr, acc[ct], 0, 0, 0);
    }
  }
  f16* vtb = vt + (size_t)b * 1536 * 4096;
#pragma unroll
  for (int ct = 0; ct < 4; ++ct) {
    int i = i0 + ct * 16 + l15;
#pragma unroll
    for (int r = 0; r < 4; ++r) {
      int k = k0 + wv * 16 + quad * 4 + r;
      float val = acc[ct][r] + bias[k];
      f16 vh = (f16)val;
      float vf = (float)vh;
      float sq = vf * vf;
      f16 sqh = (f16)sq;
      f16 sql = (f16)(sq - (float)sqh);
      vtb[(size_t)k * 4096 + i] = vh;
      vtb[(size_t)(512 + k) * 4096 + i] = sqh;
      vtb[(size_t)(1024 + k) * 4096 + i] = sql;
    }
  }
}

// ---------------------------------------------------------------------------
// adaattn_flash: per block = 32 Q-rows of one batch; 8 waves (2 rowgroups x
//   4 colgroups); M-tiles of 64. Wave (rg,cg) owns Q-rows [rg*16,+16) x
//   V cols [cg*384,+384) = 24 16x16 acc tiles (96 regs).
//   F staged once in LDS (fragment order). G + V direct per-lane global loads
//   (twin waves rg=0/1 share bytes via L1). LDS 38.4 KB.
// ---------------------------------------------------------------------------
__global__ __launch_bounds__(512, 2) void adaattn_flash(
    const f16* __restrict__ Fb, const f16* __restrict__ Gb,
    const f16* __restrict__ VT, const float* __restrict__ cx,
    float* __restrict__ out) {
  // XCD swizzle: assuming round-robin blockIdx->XCD, batch b lands on
  // XCDs {2b, 2b+1} (perf heuristic only; correctness independent).
  const int id = blockIdx.x;                       // 0..511
  const int b = (id >> 1) & 3;
  const int n0 = (((id >> 3) << 1) | (id & 1)) * 32;
  const int tid = threadIdx.x;
  const int lane = tid & 63;
  const int wvAll = tid >> 6;                      // 0..7
  const int cg = wvAll & 3;                        // colgroup
  const int rg = wvAll >> 2;                       // rowgroup
  const int l15 = lane & 15;
  const int quad = lane >> 4;

  // main: f_lds[2][16][64][8] (32768) | p_lds[2][16][72] (4608) |
  //       smax[2][64] (512) | ssum[2][64] (512)  = 38400 B
  // epilogue (aliased): meanL[128][33] (16896) | e2L[128][33] (16896)
  __shared__ __align__(16) char smem[38400];
  f16* f_lds = (f16*)smem;                  // fragment-ordered F tiles
  f16* p_lds = (f16*)(smem + 32768);        // [2][16 rows][72]
  float* smax = (float*)(smem + 37376);     // [2][4 cg][16 rows]
  float* ssum = (float*)(smem + 37888);     // [2][4 cg][16 rows]

  // stage F once: f_lds[((rg*16+ks)*64+lane)*8] = A-frag(lane) of rowgroup rg
  {
    const f16* fbase = Fb + ((size_t)b * 4096 + n0) * 512;
#pragma unroll
    for (int rep = 0; rep < 4; ++rep) {
      int fid = tid + rep * 512;            // 0..2047 = (rg, ks, lane)
      int rg2 = fid >> 10;
      int ks = (fid >> 6) & 15;
      int ln = fid & 63;
      f16x8 v = *(const f16x8*)(fbase + (size_t)(rg2 * 16 + (ln & 15)) * 512 +
                                ks * 32 + (ln >> 4) * 8);
      *(f16x8*)&f_lds[fid * 8] = v;
    }
  }

  f32x4 acc[24];
#pragma unroll
  for (int t = 0; t < 24; ++t) acc[t] = f32x4{0.f, 0.f, 0.f, 0.f};
  float m_run[4] = {-1e30f, -1e30f, -1e30f, -1e30f};
  float l_run[4] = {0.f, 0.f, 0.f, 0.f};

  // G fragment base: colgroup cg reads rows [m0+cg*16, +16)
  const f16* gbase = Gb + ((size_t)b * 4096 + cg * 16 + l15) * 512 + quad * 8;
  const f16* vb = VT + ((size_t)b * 1536 + (size_t)cg * 384 + l15) * 4096;

  __syncthreads();  // f_lds ready

  for (int m0 = 0; m0 < 4096; m0 += 64) {
    // QK: wave (rg,cg) -> logits rows [rg*16,+16) x cols [m0+cg*16,+16)
    f32x4 lg = f32x4{0.f, 0.f, 0.f, 0.f};
    {
      const f16* gp = gbase + (size_t)m0 * 512;
#pragma unroll
      for (int ks = 0; ks < 16; ++ks) {
        f16x8 ff = *(const f16x8*)&f_lds[((rg * 16 + ks) * 64 + lane) * 8];
        f16x8 gf = *(const f16x8*)(gp + ks * 32);
        lg = __builtin_amdgcn_mfma_f32_16x16x32_f16(ff, gf, lg, 0, 0, 0);
      }
    }

    // wave-local row max over 16 cols (butterfly within 16-lane groups)
    float tm[4];
#pragma unroll
    for (int r = 0; r < 4; ++r) {
      float v = lg[r];
      v = fmaxf(v, __shfl_xor(v, 1));
      v = fmaxf(v, __shfl_xor(v, 2));
      v = fmaxf(v, __shfl_xor(v, 4));
      v = fmaxf(v, __shfl_xor(v, 8));
      tm[r] = v;
    }
    if (l15 == 0) {
#pragma unroll
      for (int r = 0; r < 4; ++r) smax[rg * 64 + cg * 16 + quad * 4 + r] = tm[r];
    }
    __syncthreads();  // smax ready; also guards p_lds reuse from prev iter

    float alpha[4], ts[4];
#pragma unroll
    for (int r = 0; r < 4; ++r) {
      int row = quad * 4 + r;
      const float* sx = &smax[rg * 64];
      float mt = fmaxf(fmaxf(sx[row], sx[16 + row]),
                       fmaxf(sx[32 + row], sx[48 + row]));
      float mn = fmaxf(m_run[r], mt);
      alpha[r] = exp2f((m_run[r] - mn) * LOG2E);
      m_run[r] = mn;
      float p = exp2f((lg[r] - mn) * LOG2E);
      f16 ph = (f16)p;  // round first so weights & sums agree exactly
      p = (float)ph;
      p_lds[(rg * 16 + row) * 72 + cg * 16 + l15] = ph;
      float s = p;
      s += __shfl_xor(s, 1);
      s += __shfl_xor(s, 2);
      s += __shfl_xor(s, 4);
      s += __shfl_xor(s, 8);
      ts[r] = s;
    }
    if (l15 == 0) {
#pragma unroll
      for (int r = 0; r < 4; ++r) ssum[rg * 64 + cg * 16 + quad * 4 + r] = ts[r];
    }
    // rescale accumulators by alpha; skip when all alpha == 1 (exact identity)
    if (__any(alpha[0] != 1.f || alpha[1] != 1.f ||
              alpha[2] != 1.f || alpha[3] != 1.f)) {
#pragma unroll
      for (int t = 0; t < 24; ++t) {
#pragma unroll
        for (int r = 0; r < 4; ++r) acc[t][r] *= alpha[r];
      }
    }
    __syncthreads();  // p_lds + ssum ready

#pragma unroll
    for (int r = 0; r < 4; ++r) {
      int row = quad * 4 + r;
      const float* su = &ssum[rg * 64];
      l_run[r] = l_run[r] * alpha[r] +
                 (su[row] + su[16 + row] + su[32 + row] + su[48 + row]);
    }

    // PV: A = P (own rowgroup, from LDS), B = VT direct (L1 twin / L2 / L3)
    // FULL unroll: constant acc indices (partial unroll => scratch demotion)
    f16x8 pf0 = *(const f16x8*)&p_lds[(rg * 16 + l15) * 72 + quad * 8];
    f16x8 pf1 = *(const f16x8*)&p_lds[(rg * 16 + l15) * 72 + 32 + quad * 8];
    const f16* vp = vb + m0 + quad * 8;
#pragma unroll
    for (int ct = 0; ct < 24; ++ct) {
      f16x8 v0 = *(const f16x8*)(vp + (size_t)ct * (16 * 4096));
      f16x8 v1 = *(const f16x8*)(vp + (size_t)ct * (16 * 4096) + 32);
      acc[ct] = __builtin_amdgcn_mfma_f32_16x16x32_f16(pf0, v0, acc[ct], 0, 0, 0);
      acc[ct] = __builtin_amdgcn_mfma_f32_16x16x32_f16(pf1, v1, acc[ct], 0, 0, 0);
    }
  }

  // ---------------- epilogue (4 passes of 128 channels) ----------------
  __syncthreads();  // all p_lds/f_lds reads done before aliasing as meanL/e2L
  float inv[4];
#pragma unroll
  for (int r = 0; r < 4; ++r) inv[r] = 1.0f / l_run[r];

  float* meanL = (float*)smem;            // [128][33]
  float* e2L = (float*)(smem + 16896);    // [128][33]

#pragma unroll
  for (int q = 0; q < 4; ++q) {
    // phase 1: write mean (grp 0) and e2-hi (grp 1) for this channel quarter
#pragma unroll
    for (int ct = 0; ct < 24; ++ct) {
      int vcol = cg * 384 + ct * 16 + l15;
      int grp = vcol >> 9;
      int c = vcol & 511;
      if (grp < 2 && (c >> 7) == q) {
        float* dst = (grp == 0) ? meanL : e2L;
#pragma unroll
        for (int r = 0; r < 4; ++r)
          dst[(c & 127) * 33 + rg * 16 + quad * 4 + r] = acc[ct][r] * inv[r];
      }
    }
    __syncthreads();
    // phase 2: add e2-lo (grp 2)
#pragma unroll
    for (int ct = 0; ct < 24; ++ct) {
      int vcol = cg * 384 + ct * 16 + l15;
      int grp = vcol >> 9;
      int c = vcol & 511;
      if (grp == 2 && (c >> 7) == q) {
#pragma unroll
        for (int r = 0; r < 4; ++r)
          e2L[(c & 127) * 33 + rg * 16 + quad * 4 + r] += acc[ct][r] * inv[r];
      }
    }
    __syncthreads();

    // out[b][q*128 + c][n0+nl] = std * c_x + mean   (128 ch x 32 cols)
#pragma unroll
    for (int rep = 0; rep < 8; ++rep) {
      int idx = tid + rep * 512;  // 0..4095
      int cl = idx >> 5;          // 0..127
      int nl = idx & 31;
      float m = meanL[cl * 33 + nl];
      float e2v = e2L[cl * 33 + nl];
      float sd = sqrtf(fmaxf(e2v - m * m, 0.f));
      size_t gi = ((size_t)b * 512 + q * 128 + cl) * 4096 + n0 + nl;
      out[gi] = sd * cx[gi] + m;
    }
    __syncthreads();  // before next quarter reuses meanL/e2L
  }
}

// ---------------------------------------------------------------------------
extern "C" void kernel_launch(void* const* d_in, const int* in_sizes, int n_in,
                              void* d_out, int out_size, void* d_ws, size_t ws_size,
                              hipStream_t stream) {
  (void)in_sizes; (void)n_in; (void)out_size;
  const float* c_x  = (const float*)d_in[0];
  const float* s_x  = (const float*)d_in[1];
  const float* c_1x = (const float*)d_in[2];
  const float* s_1x = (const float*)d_in[3];
  const float* f_w  = (const float*)d_in[4];
  const float* f_b  = (const float*)d_in[5];
  const float* g_w  = (const float*)d_in[6];
  const float* g_b  = (const float*)d_in[7];
  const float* h_w  = (const float*)d_in[8];
  const float* h_b  = (const float*)d_in[9];
  float* out = (float*)d_out;

  const size_t fe = (size_t)4 * 4096 * 512;  // elements per F/G buffer
  f16* Fb = (f16*)d_ws;
  f16* Gb = Fb + fe;
  f16* VT = Gb + fe;
  const size_t need = fe * 2 * sizeof(f16) * 2 + (size_t)4 * 1536 * 4096 * sizeof(f16);
  if (ws_size < need) return;  // 80 MiB required; fail loudly (output stays poisoned)

  dim3 blk(256);
  dim3 gP(64, 8, 4);
  conv_ik<<<gP, blk, 0, stream>>>(c_1x, f_w, f_b, Fb);
  conv_ik<<<gP, blk, 0, stream>>>(s_1x, g_w, g_b, Gb);
  conv_vt<<<gP, blk, 0, stream>>>(s_x, h_w, h_b, VT);
  adaattn_flash<<<dim3(512), dim3(512), 0, stream>>>(Fb, Gb, VT, c_x, out);
}